// Round 13
// baseline (588.099 us; speedup 1.0000x reference)
//
#include <hip/hip_runtime.h>
#include <math.h>

#define NN 100000
#define NE 1600000
#define NG 1024
#define FF 128
#define SCAP 48                   // fixed slots per node row (max deg ~45)

typedef __attribute__((ext_vector_type(8))) short short8;
typedef __attribute__((ext_vector_type(4))) float f32x4;
typedef __attribute__((ext_vector_type(2))) float f32x2;

__device__ __forceinline__ unsigned short f2b(float f) {
    union { float f; unsigned u; } v; v.f = f;
    unsigned r = (v.u + 0x7FFF + ((v.u >> 16) & 1)) >> 16;
    return (unsigned short)r;
}
__device__ __forceinline__ float us2f(unsigned short u) {
    union { unsigned u; float f; } v; v.u = ((unsigned)u) << 16; return v.f;
}
// hardware ELU: v_exp_f32 is 2^x; elu(v)=v>0?v:2^(v*log2e)-1.
__device__ __forceinline__ float fast_elu(float v) {
    float e = __builtin_amdgcn_exp2f(v * 1.44269504088896340736f) - 1.0f;
    return v > 0.f ? v : e;
}
// pack 8 floats -> 8 fp8 (uint2), byte i = v[i]
__device__ __forceinline__ uint2 pk8(const float* v) {
    unsigned lo = 0, hi = 0;
    lo = (unsigned)__builtin_amdgcn_cvt_pk_fp8_f32(v[0], v[1], (int)lo, false);
    lo = (unsigned)__builtin_amdgcn_cvt_pk_fp8_f32(v[2], v[3], (int)lo, true);
    hi = (unsigned)__builtin_amdgcn_cvt_pk_fp8_f32(v[4], v[5], (int)hi, false);
    hi = (unsigned)__builtin_amdgcn_cvt_pk_fp8_f32(v[6], v[7], (int)hi, true);
    uint2 r; r.x = lo; r.y = hi; return r;
}
#define MFMA(a, b, c) __builtin_amdgcn_mfma_f32_16x16x32_bf16((a), (b), (c), 0, 0, 0)

// ---------------- single-pass edge scatter into fixed 48-slot rows ----------
// p = atomicAdd(deg[dst]); ssrc[dst*48+p] = src*128 (pre-scaled byte offset).
// No second pass, no compaction. deg[] counts ALL edges (matches reference
// mean divisor even in the ~1e-5-probability >48 case).
__global__ __launch_bounds__(256)
void edge_scatter(const int* __restrict__ src, const int* __restrict__ dst,
                  int* __restrict__ deg, int* __restrict__ ssrc, int n) {
    const int stride = gridDim.x * 1024;
    for (int i = (blockIdx.x * 256 + threadIdx.x) * 4; i < n; i += stride) {
        int4 d4 = *(const int4*)&dst[i];
        int4 s4 = *(const int4*)&src[i];
        int p;
        p = atomicAdd(&deg[d4.x], 1); if (p < SCAP) ssrc[d4.x * SCAP + p] = s4.x << 7;
        p = atomicAdd(&deg[d4.y], 1); if (p < SCAP) ssrc[d4.y * SCAP + p] = s4.y << 7;
        p = atomicAdd(&deg[d4.z], 1); if (p < SCAP) ssrc[d4.z * SCAP + p] = s4.z << 7;
        p = atomicAdd(&deg[d4.w], 1); if (p < SCAP) ssrc[d4.w * SCAP + p] = s4.w << 7;
    }
}

// ---------------- weight prep + deg-zero + graph offsets (one launch) -------
// One block per matrix (16): stage 128x128 fp32 -> bf16 into LDS (coalesced
// float4 reads), emit MFMA-fragment order with coalesced 2B writes. All
// blocks also strip-zero deg[]; blocks 0-4 compute g_off/inv_cnt via binary
// search; block 0 writes the ssrc[0] sentinel (valid gather offset for
// masked lanes; overwritten with a real offset if node 0 has edges).
struct WTab { const float* a[16]; };
__global__ __launch_bounds__(256)
void prep_weights(WTab tab, unsigned short* __restrict__ dst,
                  int* __restrict__ deg, int* __restrict__ ssrc,
                  const int* __restrict__ batch, int* __restrict__ g_off,
                  float* __restrict__ inv_cnt) {
    __shared__ unsigned short Wl[128 * 128];
    const int w = blockIdx.x;
    const int t = threadIdx.x;
    for (int i = w * 256 + t; i < NN; i += 16 * 256) deg[i] = 0;
    if (w == 0 && t == 0) ssrc[0] = 0;
    {
        int g = w * 256 + t;
        if (g <= NG) {
            if (g == NG) {
                g_off[NG] = NN;
            } else {
                int lo = 0, hi = NN;
                while (lo < hi) { int mid = (lo + hi) >> 1; if (batch[mid] < g) lo = mid + 1; else hi = mid; }
                int lo2 = lo, hi2 = NN;
                while (lo2 < hi2) { int mid = (lo2 + hi2) >> 1; if (batch[mid] < g + 1) lo2 = mid + 1; else hi2 = mid; }
                g_off[g] = lo;
                int c = lo2 - lo;
                inv_cnt[g] = 1.0f / (float)(c > 1 ? c : 1);
            }
        }
    }
    const float4* srcp = (const float4*)tab.a[w];
    for (int i = t; i < 4096; i += 256) {
        float4 v = srcp[i];
        ushort4 o = {f2b(v.x), f2b(v.y), f2b(v.z), f2b(v.w)};
        *(ushort4*)&Wl[i * 4] = o;
    }
    __syncthreads();
    unsigned short* dw = dst + (size_t)w * 16384;
    for (int i2 = 0; i2 < 64; ++i2) {
        int idx = t + i2 * 256;
        int j = idx & 7, lane = (idx >> 3) & 63, nt = (idx >> 9) & 7, kc = idx >> 12;
        int cb = lane & 15, rq = lane >> 4;
        int k = kc * 32 + rq * 8 + j;
        int n = nt * 16 + cb;
        dw[idx] = Wl[k * 128 + n];
    }
}

// ---------------- SAGE mean aggregation: TWO nodes per wave, strided rows ---
// Row i's edges live at ssrc[i*48 .. i*48+deg). Masked lanes gather via the
// ssrc[0] sentinel (always a valid h8 row offset). inv_deg computed inline.
__global__ __launch_bounds__(256)
void sage_agg(const unsigned char* __restrict__ h8, const int* __restrict__ deg,
              const int* __restrict__ ssrc, unsigned short* __restrict__ aggb) {
    const int wid = threadIdx.x >> 6;
    const int lane = threadIdx.x & 63;
    const int n0 = blockIdx.x * 8 + wid * 2;
    const int n1 = n0 + 1;
    const int eg = lane >> 4, j = lane & 15;
    const int jo = j * 8;
    const int d0 = deg[n0], d1 = deg[n1];
    const int beg0 = n0 * SCAP, beg1 = n1 * SCAP;
    const int end0 = beg0 + (d0 < SCAP ? d0 : SCAP);
    const int end1 = beg1 + (d1 < SCAP ? d1 : SCAP);
    f32x2 a0 = {0.f, 0.f}, a1 = {0.f, 0.f}, a2 = {0.f, 0.f}, a3 = {0.f, 0.f};
    f32x2 b0 = {0.f, 0.f}, b1 = {0.f, 0.f}, b2 = {0.f, 0.f}, b3 = {0.f, 0.f};
    int e0 = beg0 + eg, e1 = beg1 + eg;
    const int dm = d0 > d1 ? d0 : d1;
    const int nit = ((dm < SCAP ? dm : SCAP) + 31) >> 5;
    for (int it = 0; it < nit; ++it, e0 += 32, e1 += 32) {
        uint2 u0[8], u1[8];
        #pragma unroll
        for (int k = 0; k < 8; ++k) {
            int ek = e0 + 4 * k;
            bool ok = ek < end0;
            int idx = ssrc[ok ? ek : 0];
            uint2 uu = *(const uint2*)(h8 + (unsigned)(idx + jo));
            uu.x = ok ? uu.x : 0u;
            uu.y = ok ? uu.y : 0u;                             // fp8 0x00 -> 0.0f
            u0[k] = uu;
        }
        #pragma unroll
        for (int k = 0; k < 8; ++k) {
            int ek = e1 + 4 * k;
            bool ok = ek < end1;
            int idx = ssrc[ok ? ek : 0];
            uint2 uu = *(const uint2*)(h8 + (unsigned)(idx + jo));
            uu.x = ok ? uu.x : 0u;
            uu.y = ok ? uu.y : 0u;
            u1[k] = uu;
        }
        #pragma unroll
        for (int k = 0; k < 8; ++k) {
            a0 += __builtin_amdgcn_cvt_pk_f32_fp8(u0[k].x, false);
            a1 += __builtin_amdgcn_cvt_pk_f32_fp8(u0[k].x, true);
            a2 += __builtin_amdgcn_cvt_pk_f32_fp8(u0[k].y, false);
            a3 += __builtin_amdgcn_cvt_pk_f32_fp8(u0[k].y, true);
            b0 += __builtin_amdgcn_cvt_pk_f32_fp8(u1[k].x, false);
            b1 += __builtin_amdgcn_cvt_pk_f32_fp8(u1[k].x, true);
            b2 += __builtin_amdgcn_cvt_pk_f32_fp8(u1[k].y, false);
            b3 += __builtin_amdgcn_cvt_pk_f32_fp8(u1[k].y, true);
        }
    }
    float af[8] = {a0.x, a0.y, a1.x, a1.y, a2.x, a2.y, a3.x, a3.y};
    float bf[8] = {b0.x, b0.y, b1.x, b1.y, b2.x, b2.y, b3.x, b3.y};
    #pragma unroll
    for (int k = 0; k < 8; ++k) {
        af[k] += __shfl_xor(af[k], 16);
        af[k] += __shfl_xor(af[k], 32);
        bf[k] += __shfl_xor(bf[k], 16);
        bf[k] += __shfl_xor(bf[k], 32);
    }
    if (eg == 0) {
        float id0 = 1.0f / (float)(d0 > 1 ? d0 : 1);
        float id1 = 1.0f / (float)(d1 > 1 ? d1 : 1);
        #pragma unroll
        for (int nt = 0; nt < 8; ++nt) {
            aggb[(size_t)n0 * 128 + nt * 16 + j] = f2b(af[nt] * id0);
            aggb[(size_t)n1 * 128 + nt * 16 + j] = f2b(bf[nt] * id1);
        }
    }
}

// ---------------- mean pool per graph from bf16 (4 waves + LDS reduce) ------
__global__ __launch_bounds__(256)
void pool_mean_b(const unsigned short* __restrict__ src, const int* __restrict__ g_off,
                 const float* __restrict__ inv_cnt, float* __restrict__ out) {
    __shared__ float red[3][128];
    const int g = blockIdx.x;
    const int t = threadIdx.x;
    const int lane = t & 63, wid = t >> 6;
    const int j = lane & 15, rs = lane >> 4;
    const int beg = g_off[g], end = g_off[g + 1];
    float s[8] = {0.f, 0.f, 0.f, 0.f, 0.f, 0.f, 0.f, 0.f};
    for (int n = beg + rs + wid * 4; n < end; n += 16) {
        short8 v = *(const short8*)&src[(size_t)n * FF + j * 8];
        #pragma unroll
        for (int i = 0; i < 8; ++i) s[i] += us2f((unsigned short)v[i]);
    }
    #pragma unroll
    for (int i = 0; i < 8; ++i) {
        s[i] += __shfl_xor(s[i], 16);
        s[i] += __shfl_xor(s[i], 32);
    }
    if (wid > 0 && rs == 0) {
        #pragma unroll
        for (int i = 0; i < 8; ++i) red[wid - 1][j * 8 + i] = s[i];
    }
    __syncthreads();
    if (wid == 0 && rs == 0) {
        float ic = inv_cnt[g];
        #pragma unroll
        for (int i = 0; i < 8; ++i) {
            float v = s[i] + red[0][j * 8 + i] + red[1][j * 8 + i] + red[2][j * 8 + i];
            out[(size_t)g * FF + j * 8 + i] = v * ic;
        }
    }
}

// ---------------- MFMA bf16 GEMM: BARRIER-FREE (wave-private band stage) ----
template<bool AB16, bool R1, int RESM, int ACT, bool LN, bool OF32, bool OB16, bool OB8>
__global__ __launch_bounds__(256)
void gemm_mfma(const void* __restrict__ A_,
               const unsigned short* __restrict__ Wf,
               const float* __restrict__ bias,
               const float* __restrict__ rvec, const float* __restrict__ rrow,
               const float* __restrict__ res,
               const float* __restrict__ lng, const float* __restrict__ lnb,
               float* __restrict__ outf, unsigned short* __restrict__ outb,
               unsigned char* __restrict__ outb8, int M) {
    __shared__ short Al[64 * 136];

    const int t = threadIdx.x;
    const int lane = t & 63, wid = t >> 6;
    const int m0 = blockIdx.x * 64;
    const int cb = lane & 15, rq = lane >> 4;
    const int band = wid * 16;

    if (AB16) {
        const unsigned short* Ab = (const unsigned short*)A_;
        #pragma unroll
        for (int i2 = 0; i2 < 4; ++i2) {
            int i = lane + i2 * 64;
            int row = band + (i >> 4), seg = i & 15;
            int gr = m0 + row; if (gr >= M) gr = M - 1;
            *(uint4*)&Al[row * 136 + seg * 8] = *(const uint4*)&Ab[(size_t)gr * 128 + seg * 8];
        }
    } else {
        const float* Af = (const float*)A_;
        #pragma unroll
        for (int i2 = 0; i2 < 8; ++i2) {
            int i = lane + i2 * 64;
            int row = band + (i >> 5), seg = i & 31;
            int gr = m0 + row; if (gr >= M) gr = M - 1;
            float4 v = *(const float4*)&Af[(size_t)gr * 128 + seg * 4];
            ushort4 o = {f2b(v.x), f2b(v.y), f2b(v.z), f2b(v.w)};
            *(ushort4*)&Al[row * 136 + seg * 4] = o;
        }
    }
    // no barrier: all LDS traffic is band-local (same wave wrote it)

    f32x4 acc[8];
    #pragma unroll
    for (int nt = 0; nt < 8; ++nt) acc[nt] = (f32x4){0.f, 0.f, 0.f, 0.f};

    const int aoff_base = (band + cb) * 136 + rq * 8;
    for (int kc = 0; kc < 4; ++kc) {
        short8 a0 = *(const short8*)&Al[aoff_base + kc * 32];
        #pragma unroll
        for (int nt = 0; nt < 8; ++nt) {
            short8 b0 = *(const short8*)&Wf[(size_t)(kc * 8 + nt) * 512 + lane * 8];
            acc[nt] = MFMA(a0, b0, acc[nt]);
        }
    }

    float bs[8], rr[8], lg[8], lb[8];
    #pragma unroll
    for (int nt = 0; nt < 8; ++nt) {
        int col = nt * 16 + cb;
        bs[nt] = bias[col];
        if (R1) rr[nt] = rrow[col];
        if (LN) { lg[nt] = lng[col]; lb[nt] = lnb[col]; }
    }
    #pragma unroll
    for (int reg = 0; reg < 4; ++reg) {
        int m = m0 + band + rq * 4 + reg;
        int mc = m < M ? m : M - 1;
        float v[8];
        #pragma unroll
        for (int nt = 0; nt < 8; ++nt) v[nt] = acc[nt][reg] + bs[nt];
        if (R1) {
            float rv = rvec[mc];
            #pragma unroll
            for (int nt = 0; nt < 8; ++nt) v[nt] += rv * rr[nt];
        }
        if (RESM == 1) {
            #pragma unroll
            for (int nt = 0; nt < 8; ++nt) v[nt] += res[(size_t)mc * 128 + nt * 16 + cb];
        }
        if (ACT == 1) {
            #pragma unroll
            for (int nt = 0; nt < 8; ++nt) v[nt] = fast_elu(v[nt]);
        }
        if (LN) {
            float s1 = 0.f, s2 = 0.f;
            #pragma unroll
            for (int nt = 0; nt < 8; ++nt) { s1 += v[nt]; s2 += v[nt] * v[nt]; }
            #pragma unroll
            for (int o = 8; o >= 1; o >>= 1) { s1 += __shfl_xor(s1, o); s2 += __shfl_xor(s2, o); }
            float mu = s1 * (1.f / 128.f);
            float rs = rsqrtf(s2 * (1.f / 128.f) - mu * mu + 1e-5f);
            #pragma unroll
            for (int nt = 0; nt < 8; ++nt) v[nt] = (v[nt] - mu) * rs * lg[nt] + lb[nt];
        }
        if (m < M) {
            #pragma unroll
            for (int nt = 0; nt < 8; ++nt) {
                size_t o = (size_t)m * 128 + nt * 16 + cb;
                if (OF32) outf[o] = v[nt];
                if (OB16) outb[o] = f2b(v[nt]);
            }
            if (OB8) *(uint2*)&outb8[(size_t)m * 128 + cb * 8] = pk8(v);
        }
    }
}

// ---------------- fused GEMM chain: BARRIER-FREE, h IN-PLACE ---------------
// Each wave owns rows band..band+15 end-to-end (stage, GEMM, LN1, FF1, FF2,
// final write) -> hout may equal hin (each row read only by the wave that
// rewrites it).
__global__ __launch_bounds__(256)
void gc_chain(const unsigned short* __restrict__ hin, const unsigned short* __restrict__ aggb,
              unsigned short* __restrict__ hout, unsigned char* __restrict__ h8out,
              const unsigned short* __restrict__ Wl_f, const unsigned short* __restrict__ Wr_f,
              const unsigned short* __restrict__ W1_f, const unsigned short* __restrict__ W2_f,
              const float* __restrict__ bl,
              const float* __restrict__ g1, const float* __restrict__ b1,
              const float* __restrict__ bb1, const float* __restrict__ bb2,
              const float* __restrict__ g2, const float* __restrict__ b2, int M) {
    __shared__ short Hl[64 * 136];     // h tile -> y1 tile
    __shared__ short Gl[64 * 136];     // agg tile -> elu(t) tile

    const int t = threadIdx.x;
    const int lane = t & 63, wid = t >> 6;
    const int m0 = blockIdx.x * 64;
    const int cb = lane & 15, rq = lane >> 4;
    const int band = wid * 16;
    const int aoff_base = (band + cb) * 136 + rq * 8;
    const int boff = lane * 8;

    #pragma unroll
    for (int i2 = 0; i2 < 4; ++i2) {
        int i = lane + i2 * 64;
        int row = band + (i >> 4), seg = i & 15;
        int gr = m0 + row; if (gr >= M) gr = M - 1;
        *(uint4*)&Hl[row * 136 + seg * 8] = *(const uint4*)&hin[(size_t)gr * 128 + seg * 8];
        *(uint4*)&Gl[row * 136 + seg * 8] = *(const uint4*)&aggb[(size_t)gr * 128 + seg * 8];
    }
    // no barrier: band-local LDS only

    f32x4 acc[8];
    #pragma unroll
    for (int nt = 0; nt < 8; ++nt) acc[nt] = (f32x4){0.f, 0.f, 0.f, 0.f};

    // ---- dual GEMM: acc = agg@Wl + h@Wr ----
    for (int kc = 0; kc < 4; ++kc) {
        short8 a0 = *(const short8*)&Gl[aoff_base + kc * 32];
        short8 a1 = *(const short8*)&Hl[aoff_base + kc * 32];
        #pragma unroll
        for (int nt = 0; nt < 8; ++nt) {
            const size_t wo = (size_t)(kc * 8 + nt) * 512 + boff;
            acc[nt] = MFMA(a0, *(const short8*)&Wl_f[wo], acc[nt]);
            acc[nt] = MFMA(a1, *(const short8*)&Wr_f[wo], acc[nt]);
        }
    }

    // ---- epilogue 1 (band-local): y1 = LN1(acc + bl + h) -> Hl + regs ----
    float y1r[4][8];
    {
        float bs[8], lg[8], lb[8];
        #pragma unroll
        for (int nt = 0; nt < 8; ++nt) {
            int col = nt * 16 + cb;
            bs[nt] = bl[col]; lg[nt] = g1[col]; lb[nt] = b1[col];
        }
        #pragma unroll
        for (int reg = 0; reg < 4; ++reg) {
            int r = band + rq * 4 + reg;
            float v[8];
            float s1 = 0.f, s2 = 0.f;
            #pragma unroll
            for (int nt = 0; nt < 8; ++nt) {
                v[nt] = acc[nt][reg] + bs[nt] + us2f((unsigned short)Hl[r * 136 + nt * 16 + cb]);
                s1 += v[nt]; s2 += v[nt] * v[nt];
            }
            #pragma unroll
            for (int o = 8; o >= 1; o >>= 1) { s1 += __shfl_xor(s1, o); s2 += __shfl_xor(s2, o); }
            float mu = s1 * (1.f / 128.f);
            float rs = rsqrtf(s2 * (1.f / 128.f) - mu * mu + 1e-5f);
            #pragma unroll
            for (int nt = 0; nt < 8; ++nt) {
                float y = (v[nt] - mu) * rs * lg[nt] + lb[nt];
                y1r[reg][nt] = y;
                Hl[r * 136 + nt * 16 + cb] = (short)f2b(y);
            }
        }
    }

    // ---- FF1 (band-local): t = elu(y1@W1 + bb1) -> Gl ----
    #pragma unroll
    for (int nt = 0; nt < 8; ++nt) acc[nt] = (f32x4){0.f, 0.f, 0.f, 0.f};
    for (int kc = 0; kc < 4; ++kc) {
        short8 a0 = *(const short8*)&Hl[aoff_base + kc * 32];
        #pragma unroll
        for (int nt = 0; nt < 8; ++nt)
            acc[nt] = MFMA(a0, *(const short8*)&W1_f[(size_t)(kc * 8 + nt) * 512 + boff], acc[nt]);
    }
    {
        float bs[8];
        #pragma unroll
        for (int nt = 0; nt < 8; ++nt) bs[nt] = bb1[nt * 16 + cb];
        #pragma unroll
        for (int reg = 0; reg < 4; ++reg) {
            int r = band + rq * 4 + reg;
            #pragma unroll
            for (int nt = 0; nt < 8; ++nt) {
                float v = fast_elu(acc[nt][reg] + bs[nt]);
                Gl[r * 136 + nt * 16 + cb] = (short)f2b(v);
            }
        }
    }

    // ---- FF2 (band-local): h' = LN2(t@W2 + bb2 + y1) -> global bf16 + fp8 --
    #pragma unroll
    for (int nt = 0; nt < 8; ++nt) acc[nt] = (f32x4){0.f, 0.f, 0.f, 0.f};
    for (int kc = 0; kc < 4; ++kc) {
        short8 a0 = *(const short8*)&Gl[aoff_base + kc * 32];
        #pragma unroll
        for (int nt = 0; nt < 8; ++nt)
            acc[nt] = MFMA(a0, *(const short8*)&W2_f[(size_t)(kc * 8 + nt) * 512 + boff], acc[nt]);
    }
    {
        float bs[8], lg[8], lb[8];
        #pragma unroll
        for (int nt = 0; nt < 8; ++nt) {
            int col = nt * 16 + cb;
            bs[nt] = bb2[col]; lg[nt] = g2[col]; lb[nt] = b2[col];
        }
        #pragma unroll
        for (int reg = 0; reg < 4; ++reg) {
            int r = band + rq * 4 + reg;
            int m = m0 + r;
            float v[8];
            float s1 = 0.f, s2 = 0.f;
            #pragma unroll
            for (int nt = 0; nt < 8; ++nt) {
                v[nt] = acc[nt][reg] + bs[nt] + y1r[reg][nt];
                s1 += v[nt]; s2 += v[nt] * v[nt];
            }
            #pragma unroll
            for (int o = 8; o >= 1; o >>= 1) { s1 += __shfl_xor(s1, o); s2 += __shfl_xor(s2, o); }
            float mu = s1 * (1.f / 128.f);
            float rs = rsqrtf(s2 * (1.f / 128.f) - mu * mu + 1e-5f);
            if (m < M) {
                float fv[8];
                #pragma unroll
                for (int nt = 0; nt < 8; ++nt) {
                    fv[nt] = (v[nt] - mu) * rs * lg[nt] + lb[nt];
                    hout[(size_t)m * 128 + nt * 16 + cb] = f2b(fv[nt]);
                }
                *(uint2*)&h8out[(size_t)m * 128 + cb * 8] = pk8(fv);
            }
        }
    }
}

// ---------------- fused head: BARRIER-FREE band-local chain -----------------
__global__ __launch_bounds__(256)
void head_chain(const float* __restrict__ gm,
                const unsigned short* __restrict__ Wa_f,
                const unsigned short* __restrict__ P1_f,
                const unsigned short* __restrict__ P2_f,
                const float* __restrict__ mdfb,
                const float* __restrict__ g1, const float* __restrict__ b1,
                const float* __restrict__ p1b, const float* __restrict__ p2b,
                const float* __restrict__ g2, const float* __restrict__ b2,
                float* __restrict__ outp) {
    __shared__ short Al[64 * 136];

    const int t = threadIdx.x;
    const int lane = t & 63, wid = t >> 6;
    const int m0 = blockIdx.x * 64;
    const int cb = lane & 15, rq = lane >> 4;
    const int band = wid * 16;
    const int aoff_base = (band + cb) * 136 + rq * 8;
    const int boff = lane * 8;

    #pragma unroll
    for (int i2 = 0; i2 < 8; ++i2) {
        int i = lane + i2 * 64;
        int row = band + (i >> 5), seg = i & 31;
        float4 v = *(const float4*)&gm[(size_t)(m0 + row) * 128 + seg * 4];
        ushort4 o = {f2b(v.x), f2b(v.y), f2b(v.z), f2b(v.w)};
        *(ushort4*)&Al[row * 136 + seg * 4] = o;
    }
    // no barrier: band-local LDS only

    f32x4 acc[8];
    // ---- GEMM1: gm@Wa + mdfb, LN1 -> y1r + Al ----
    #pragma unroll
    for (int nt = 0; nt < 8; ++nt) acc[nt] = (f32x4){0.f, 0.f, 0.f, 0.f};
    for (int kc = 0; kc < 4; ++kc) {
        short8 a0 = *(const short8*)&Al[aoff_base + kc * 32];
        #pragma unroll
        for (int nt = 0; nt < 8; ++nt)
            acc[nt] = MFMA(a0, *(const short8*)&Wa_f[(size_t)(kc * 8 + nt) * 512 + boff], acc[nt]);
    }
    float y1r[4][8];
    {
        float bs[8], lg[8], lb[8];
        #pragma unroll
        for (int nt = 0; nt < 8; ++nt) {
            int col = nt * 16 + cb;
            bs[nt] = mdfb[col]; lg[nt] = g1[col]; lb[nt] = b1[col];
        }
        #pragma unroll
        for (int reg = 0; reg < 4; ++reg) {
            int r = band + rq * 4 + reg;
            float v[8];
            float s1 = 0.f, s2 = 0.f;
            #pragma unroll
            for (int nt = 0; nt < 8; ++nt) {
                v[nt] = acc[nt][reg] + bs[nt];
                s1 += v[nt]; s2 += v[nt] * v[nt];
            }
            #pragma unroll
            for (int o = 8; o >= 1; o >>= 1) { s1 += __shfl_xor(s1, o); s2 += __shfl_xor(s2, o); }
            float mu = s1 * (1.f / 128.f);
            float rs = rsqrtf(s2 * (1.f / 128.f) - mu * mu + 1e-5f);
            #pragma unroll
            for (int nt = 0; nt < 8; ++nt) {
                float y = (v[nt] - mu) * rs * lg[nt] + lb[nt];
                y1r[reg][nt] = y;
                Al[r * 136 + nt * 16 + cb] = (short)f2b(y);
            }
        }
    }

    // ---- GEMM2: elu(y1@P1 + p1b) -> Al ----
    #pragma unroll
    for (int nt = 0; nt < 8; ++nt) acc[nt] = (f32x4){0.f, 0.f, 0.f, 0.f};
    for (int kc = 0; kc < 4; ++kc) {
        short8 a0 = *(const short8*)&Al[aoff_base + kc * 32];
        #pragma unroll
        for (int nt = 0; nt < 8; ++nt)
            acc[nt] = MFMA(a0, *(const short8*)&P1_f[(size_t)(kc * 8 + nt) * 512 + boff], acc[nt]);
    }
    {
        float bs[8];
        #pragma unroll
        for (int nt = 0; nt < 8; ++nt) bs[nt] = p1b[nt * 16 + cb];
        #pragma unroll
        for (int reg = 0; reg < 4; ++reg) {
            int r = band + rq * 4 + reg;
            #pragma unroll
            for (int nt = 0; nt < 8; ++nt) {
                float v = fast_elu(acc[nt][reg] + bs[nt]);
                Al[r * 136 + nt * 16 + cb] = (short)f2b(v);
            }
        }
    }

    // ---- GEMM3: LN2(t@P2 + p2b + y1r) -> out fp32 ----
    #pragma unroll
    for (int nt = 0; nt < 8; ++nt) acc[nt] = (f32x4){0.f, 0.f, 0.f, 0.f};
    for (int kc = 0; kc < 4; ++kc) {
        short8 a0 = *(const short8*)&Al[aoff_base + kc * 32];
        #pragma unroll
        for (int nt = 0; nt < 8; ++nt)
            acc[nt] = MFMA(a0, *(const short8*)&P2_f[(size_t)(kc * 8 + nt) * 512 + boff], acc[nt]);
    }
    {
        float bs[8], lg[8], lb[8];
        #pragma unroll
        for (int nt = 0; nt < 8; ++nt) {
            int col = nt * 16 + cb;
            bs[nt] = p2b[col]; lg[nt] = g2[col]; lb[nt] = b2[col];
        }
        #pragma unroll
        for (int reg = 0; reg < 4; ++reg) {
            int r = band + rq * 4 + reg;
            int m = m0 + r;
            float v[8];
            float s1 = 0.f, s2 = 0.f;
            #pragma unroll
            for (int nt = 0; nt < 8; ++nt) {
                v[nt] = acc[nt][reg] + bs[nt] + y1r[reg][nt];
                s1 += v[nt]; s2 += v[nt] * v[nt];
            }
            #pragma unroll
            for (int o = 8; o >= 1; o >>= 1) { s1 += __shfl_xor(s1, o); s2 += __shfl_xor(s2, o); }
            float mu = s1 * (1.f / 128.f);
            float rs = rsqrtf(s2 * (1.f / 128.f) - mu * mu + 1e-5f);
            #pragma unroll
            for (int nt = 0; nt < 8; ++nt)
                outp[(size_t)m * 128 + nt * 16 + cb] = (v[nt] - mu) * rs * lg[nt] + lb[nt];
        }
    }
}

extern "C" void kernel_launch(void* const* d_in, const int* in_sizes, int n_in,
                              void* d_out, int out_size, void* d_ws, size_t ws_size,
                              hipStream_t stream) {
    const float* x      = (const float*)d_in[0];
    const float* w      = (const float*)d_in[1];
    const int*   ei     = (const int*)d_in[2];
    const int*   batch  = (const int*)d_in[3];
    const float* W_in   = (const float*)d_in[4];
    const float* b_in   = (const float*)d_in[5];
    const float* sage_Wl = (const float*)d_in[6];
    const float* sage_bl = (const float*)d_in[7];
    const float* sage_Wr = (const float*)d_in[8];
    const float* ln1_g  = (const float*)d_in[9];
    const float* ln1_b  = (const float*)d_in[10];
    const float* lin1_W = (const float*)d_in[11];
    const float* lin1_b = (const float*)d_in[12];
    const float* lin2_W = (const float*)d_in[13];
    const float* lin2_b = (const float*)d_in[14];
    const float* ln2_g  = (const float*)d_in[15];
    const float* ln2_b  = (const float*)d_in[16];
    const float* mdf_W  = (const float*)d_in[17];
    const float* mdf_b  = (const float*)d_in[18];
    const float* pln1_g = (const float*)d_in[19];
    const float* pln1_b = (const float*)d_in[20];
    const float* plin1_W = (const float*)d_in[21];
    const float* plin1_b = (const float*)d_in[22];
    const float* plin2_W = (const float*)d_in[23];
    const float* plin2_b = (const float*)d_in[24];
    const float* pln2_g = (const float*)d_in[25];
    const float* pln2_b = (const float*)d_in[26];
    float* out = (float*)d_out;

    const int* e_src = ei;
    const int* e_dst = ei + NE;

    // ---- workspace layout ----
    float* ws = (float*)d_ws;
    size_t off = 0;
    float* gm      = ws + off; off += (size_t)NG * FF;
    float* inv_cnt = ws + off; off += NG;
    unsigned short* us = (unsigned short*)(ws + off);
    size_t uoff = 0;
    unsigned short* hb0  = us + uoff; uoff += (size_t)NN * FF;
    unsigned short* aggb = us + uoff; uoff += (size_t)NN * FF;
    unsigned short* wt   = us + uoff; uoff += (size_t)16 * 16384;
    int* iw = (int*)(us + uoff);
    size_t ioff = 0;
    int* ssrc  = iw; ioff += (size_t)NN * SCAP;
    int* deg   = iw + ioff; ioff += NN;
    int* g_off = iw + ioff; ioff += NG + 1;
    unsigned char* h8 = (unsigned char*)(iw + ioff);   // NN*128 bytes

    // ---- weight prep + deg-zero + graph offsets (one launch) ----
    WTab tab;
    tab.a[0] = W_in;
    for (int l = 0; l < 3; ++l) {
        tab.a[1 + l]  = sage_Wl + (size_t)l * 16384;
        tab.a[4 + l]  = sage_Wr + (size_t)l * 16384;
        tab.a[7 + l]  = lin1_W + (size_t)l * 16384;
        tab.a[10 + l] = lin2_W + (size_t)l * 16384;
    }
    tab.a[13] = mdf_W;      // first 128 rows only (Wa)
    tab.a[14] = plin1_W;
    tab.a[15] = plin2_W;
    prep_weights<<<16, 256, 0, stream>>>(tab, wt, deg, ssrc, batch, g_off, inv_cnt);
    const unsigned short* win_t = wt + 0 * 16384;
    const unsigned short* wa_t  = wt + 13 * 16384;
    const unsigned short* p1_t  = wt + 14 * 16384;
    const unsigned short* p2_t  = wt + 15 * 16384;

    // ---- single-pass edge scatter (no CSR compaction) ----
    edge_scatter<<<1024, 256, 0, stream>>>(e_src, e_dst, deg, ssrc, NE);

    const int GN = (NN + 63) / 64;     // 1563
    const int GB = NG / 64;            // 16

    // ---- input linear: hb0 (bf16) + h8 (fp8, permuted) ----
    gemm_mfma<false, true, 0, 0, false, false, true, true><<<GN, 256, 0, stream>>>(
        x, win_t, b_in, w, W_in + 128 * 128,
        nullptr, nullptr, nullptr, nullptr, hb0, h8, NN);

    // ---- 3 GC blocks: fp8 gather + fused GEMM chain (h in-place) ----
    for (int l = 0; l < 3; ++l) {
        sage_agg<<<NN / 8, 256, 0, stream>>>(h8, deg, ssrc, aggb);
        gc_chain<<<GN, 256, 0, stream>>>(
            hb0, aggb, hb0, h8,
            wt + (size_t)(1 + l) * 16384, wt + (size_t)(4 + l) * 16384,
            wt + (size_t)(7 + l) * 16384, wt + (size_t)(10 + l) * 16384,
            sage_bl + (size_t)l * FF,
            ln1_g + (size_t)l * FF, ln1_b + (size_t)l * FF,
            lin1_b + (size_t)l * FF, lin2_b + (size_t)l * FF,
            ln2_g + (size_t)l * FF, ln2_b + (size_t)l * FF, NN);
    }

    // ---- head: pool(h2) -> fused LN1/FF/LN2 chain (one launch) ----
    pool_mean_b<<<NG, 256, 0, stream>>>(hb0, g_off, inv_cnt, gm);
    head_chain<<<GB, 256, 0, stream>>>(
        gm, wa_t, p1_t, p2_t, mdf_b,
        pln1_g, pln1_b, plin1_b, plin2_b, pln2_g, pln2_b, out);
}

// Round 14
// 488.028 us; speedup vs baseline: 1.2051x; 1.2051x over previous
//
#include <hip/hip_runtime.h>
#include <math.h>

#define NN 100000
#define NE 1600000
#define NG 1024
#define FF 128
#define BSH 9
#define NBK ((NN + 511) >> BSH)   // 196 buckets of 512 nodes
#define RB 512                    // radix blocks
#define BCAP 16384                // fixed bucket capacity (mean 8192, sigma~90)

typedef __attribute__((ext_vector_type(8))) short short8;
typedef __attribute__((ext_vector_type(4))) float f32x4;
typedef __attribute__((ext_vector_type(2))) float f32x2;

__device__ __forceinline__ unsigned short f2b(float f) {
    union { float f; unsigned u; } v; v.f = f;
    unsigned r = (v.u + 0x7FFF + ((v.u >> 16) & 1)) >> 16;
    return (unsigned short)r;
}
__device__ __forceinline__ float us2f(unsigned short u) {
    union { unsigned u; float f; } v; v.u = ((unsigned)u) << 16; return v.f;
}
// hardware ELU: v_exp_f32 is 2^x; elu(v)=v>0?v:2^(v*log2e)-1.
__device__ __forceinline__ float fast_elu(float v) {
    float e = __builtin_amdgcn_exp2f(v * 1.44269504088896340736f) - 1.0f;
    return v > 0.f ? v : e;
}
// pack 8 floats -> 8 fp8 (uint2), byte i = v[i]
__device__ __forceinline__ uint2 pk8(const float* v) {
    unsigned lo = 0, hi = 0;
    lo = (unsigned)__builtin_amdgcn_cvt_pk_fp8_f32(v[0], v[1], (int)lo, false);
    lo = (unsigned)__builtin_amdgcn_cvt_pk_fp8_f32(v[2], v[3], (int)lo, true);
    hi = (unsigned)__builtin_amdgcn_cvt_pk_fp8_f32(v[4], v[5], (int)hi, false);
    hi = (unsigned)__builtin_amdgcn_cvt_pk_fp8_f32(v[6], v[7], (int)hi, true);
    uint2 r; r.x = lo; r.y = hi; return r;
}
#define MFMA(a, b, c) __builtin_amdgcn_mfma_f32_16x16x32_bf16((a), (b), (c), 0, 0, 0)

// ---------------- pass 1: scatter packed (src<<9|local) into padded buckets -
// Quad-vectorized streaming (int4 loads; NE divisible by 4, per aligned to 4).
__global__ __launch_bounds__(256)
void radix_scatter(const int* __restrict__ src, const int* __restrict__ dst,
                   int* __restrict__ bcur, unsigned* __restrict__ pairs, int n) {
    __shared__ int base[NBK];
    __shared__ int cnt[NBK];
    for (int i = threadIdx.x; i < NBK; i += 256) cnt[i] = 0;
    __syncthreads();
    const int per = (((n + RB - 1) / RB) + 3) & ~3;
    const int beg = blockIdx.x * per;
    const int end = min(n, beg + per);
    {
        int i = beg + 4 * (int)threadIdx.x;
        for (; i + 3 < end; i += 1024) {
            int4 d4 = *(const int4*)&dst[i];
            atomicAdd(&cnt[d4.x >> BSH], 1);
            atomicAdd(&cnt[d4.y >> BSH], 1);
            atomicAdd(&cnt[d4.z >> BSH], 1);
            atomicAdd(&cnt[d4.w >> BSH], 1);
        }
        for (; i < end; ++i) atomicAdd(&cnt[dst[i] >> BSH], 1);
    }
    __syncthreads();
    for (int i = threadIdx.x; i < NBK; i += 256)
        base[i] = cnt[i] ? atomicAdd(&bcur[i], cnt[i]) : 0;
    __syncthreads();
    {
        int i = beg + 4 * (int)threadIdx.x;
        for (; i + 3 < end; i += 1024) {
            int4 d4 = *(const int4*)&dst[i];
            int4 s4 = *(const int4*)&src[i];
            int p;
            p = atomicAdd(&base[d4.x >> BSH], 1);
            pairs[p] = ((unsigned)s4.x << BSH) | (unsigned)(d4.x & 511);
            p = atomicAdd(&base[d4.y >> BSH], 1);
            pairs[p] = ((unsigned)s4.y << BSH) | (unsigned)(d4.y & 511);
            p = atomicAdd(&base[d4.z >> BSH], 1);
            pairs[p] = ((unsigned)s4.z << BSH) | (unsigned)(d4.z & 511);
            p = atomicAdd(&base[d4.w >> BSH], 1);
            pairs[p] = ((unsigned)s4.w << BSH) | (unsigned)(d4.w & 511);
        }
        for (; i < end; ++i) {
            int d = dst[i];
            int p = atomicAdd(&base[d >> BSH], 1);
            pairs[p] = ((unsigned)src[i] << BSH) | (unsigned)(d & 511);
        }
    }
}

// ---------------- pass 2: per-bucket hist+scan+scatter -> padded CSR --------
// 512 threads (8 waves), quad-vectorized streaming. Also absorbs the old
// graph_offsets kernel: blocks 0-2 compute g_off/inv_cnt (independent work).
// ssrc stores PRE-SCALED byte offsets (src*128).
__global__ __launch_bounds__(512)
void bucket_build(const unsigned* __restrict__ pairs, const int* __restrict__ bcur,
                  int* __restrict__ row_beg, int* __restrict__ row_end,
                  float* __restrict__ inv_deg, int* __restrict__ ssrc,
                  const int* __restrict__ batch, int* __restrict__ g_off,
                  float* __restrict__ inv_cnt) {
    __shared__ int cnt[512];
    __shared__ int curs[512];
    __shared__ int wsum[8];
    const int b = blockIdx.x;
    const int n0 = b << BSH;
    const int t = threadIdx.x;
    const int lane = t & 63, wid = t >> 6;

    // folded graph_offsets: g in [0, NG], handled by blocks 0..2
    {
        int g = b * 512 + t;
        if (g <= NG) {
            if (g == NG) {
                g_off[NG] = NN;
            } else {
                int lo = 0, hi = NN;
                while (lo < hi) { int mid = (lo + hi) >> 1; if (batch[mid] < g) lo = mid + 1; else hi = mid; }
                int lo2 = lo, hi2 = NN;
                while (lo2 < hi2) { int mid = (lo2 + hi2) >> 1; if (batch[mid] < g + 1) lo2 = mid + 1; else hi2 = mid; }
                g_off[g] = lo;
                int c = lo2 - lo;
                inv_cnt[g] = 1.0f / (float)(c > 1 ? c : 1);
            }
        }
    }

    cnt[t] = 0;
    __syncthreads();
    const int beg = b * BCAP, end = bcur[b];
    {
        int i = beg + 4 * t;
        for (; i + 3 < end; i += 2048) {
            uint4 p4 = *(const uint4*)&pairs[i];
            atomicAdd(&cnt[p4.x & 511], 1);
            atomicAdd(&cnt[p4.y & 511], 1);
            atomicAdd(&cnt[p4.z & 511], 1);
            atomicAdd(&cnt[p4.w & 511], 1);
        }
        for (; i < end; ++i) atomicAdd(&cnt[pairs[i] & 511], 1);
    }
    __syncthreads();

    int c = cnt[t];
    int x = c;
    #pragma unroll
    for (int o = 1; o < 64; o <<= 1) {
        int y = __shfl_up(x, o);
        if (lane >= o) x += y;
    }
    if (lane == 63) wsum[wid] = x;
    __syncthreads();
    if (t == 0) {
        int s = 0;
        #pragma unroll
        for (int w2 = 0; w2 < 8; ++w2) { int tv = wsum[w2]; wsum[w2] = s; s += tv; }
    }
    __syncthreads();
    int g0 = beg + wsum[wid] + x - c;   // exclusive prefix
    curs[t] = g0;
    {
        int node = n0 + t;
        if (node < NN) {
            row_beg[node] = g0; row_end[node] = g0 + c;
            inv_deg[node] = 1.0f / (float)(c > 1 ? c : 1);
        }
    }
    __syncthreads();
    {
        int i = beg + 4 * t;
        for (; i + 3 < end; i += 2048) {
            uint4 p4 = *(const uint4*)&pairs[i];
            int p;
            p = atomicAdd(&curs[p4.x & 511], 1); ssrc[p] = (int)(p4.x >> BSH) << 7;
            p = atomicAdd(&curs[p4.y & 511], 1); ssrc[p] = (int)(p4.y >> BSH) << 7;
            p = atomicAdd(&curs[p4.z & 511], 1); ssrc[p] = (int)(p4.z >> BSH) << 7;
            p = atomicAdd(&curs[p4.w & 511], 1); ssrc[p] = (int)(p4.w >> BSH) << 7;
        }
        for (; i < end; ++i) {
            unsigned pr = pairs[i];
            int p = atomicAdd(&curs[pr & 511], 1);
            ssrc[p] = (int)(pr >> BSH) << 7;
        }
    }
}

// ---------------- weight prep: coalesced via LDS staging --------------------
// One block per matrix: stage 128x128 fp32 -> bf16 into LDS with fully
// coalesced float4 reads, then emit MFMA-fragment order with coalesced
// 2B writes. Block 0 also inits bucket cursors + the ssrc[0] sentinel.
struct WTab { const float* a[16]; };
__global__ __launch_bounds__(256)
void prep_weights(WTab tab, unsigned short* __restrict__ dst,
                  int* __restrict__ bcur, int* __restrict__ ssrc) {
    __shared__ unsigned short Wl[128 * 128];
    const int w = blockIdx.x;
    const int t = threadIdx.x;
    if (w == 0) {
        for (int i = t; i < NBK; i += 256) bcur[i] = i * BCAP;
        if (t == 0) ssrc[0] = 0;   // sentinel: valid gather offset
    }
    const float4* src = (const float4*)tab.a[w];
    for (int i = t; i < 4096; i += 256) {
        float4 v = src[i];
        ushort4 o = {f2b(v.x), f2b(v.y), f2b(v.z), f2b(v.w)};
        *(ushort4*)&Wl[i * 4] = o;
    }
    __syncthreads();
    unsigned short* dw = dst + (size_t)w * 16384;
    for (int i2 = 0; i2 < 64; ++i2) {
        int idx = t + i2 * 256;
        int j = idx & 7, lane = (idx >> 3) & 63, nt = (idx >> 9) & 7, kc = idx >> 12;
        int cb = lane & 15, rq = lane >> 4;
        int k = kc * 32 + rq * 8 + j;
        int n = nt * 16 + cb;
        dw[idx] = Wl[k * 128 + n];
    }
}

// ---------------- SAGE mean aggregation: TWO nodes per wave -----------------
__global__ __launch_bounds__(256)
void sage_agg(const unsigned char* __restrict__ h8, const int* __restrict__ row_beg,
              const int* __restrict__ row_end, const float* __restrict__ inv_deg,
              const int* __restrict__ ssrc, unsigned short* __restrict__ aggb) {
    const int wid = threadIdx.x >> 6;
    const int lane = threadIdx.x & 63;
    const int n0 = blockIdx.x * 8 + wid * 2;
    const int n1 = n0 + 1;
    const int eg = lane >> 4, j = lane & 15;
    const int jo = j * 8;
    const int beg0 = row_beg[n0], end0 = row_end[n0];
    const int beg1 = row_beg[n1], end1 = row_end[n1];
    f32x2 a0 = {0.f, 0.f}, a1 = {0.f, 0.f}, a2 = {0.f, 0.f}, a3 = {0.f, 0.f};
    f32x2 b0 = {0.f, 0.f}, b1 = {0.f, 0.f}, b2 = {0.f, 0.f}, b3 = {0.f, 0.f};
    int e0 = beg0 + eg, e1 = beg1 + eg;
    const int d0 = end0 - beg0, d1 = end1 - beg1;
    const int nit = ((d0 > d1 ? d0 : d1) + 31) >> 5;
    for (int it = 0; it < nit; ++it, e0 += 32, e1 += 32) {
        uint2 u0[8], u1[8];
        #pragma unroll
        for (int k = 0; k < 8; ++k) {
            int ek = e0 + 4 * k;
            bool ok = ek < end0;
            int idx = ssrc[ok ? ek : 0];
            uint2 uu = *(const uint2*)(h8 + (unsigned)(idx + jo));
            uu.x = ok ? uu.x : 0u;
            uu.y = ok ? uu.y : 0u;                             // fp8 0x00 -> 0.0f
            u0[k] = uu;
        }
        #pragma unroll
        for (int k = 0; k < 8; ++k) {
            int ek = e1 + 4 * k;
            bool ok = ek < end1;
            int idx = ssrc[ok ? ek : 0];
            uint2 uu = *(const uint2*)(h8 + (unsigned)(idx + jo));
            uu.x = ok ? uu.x : 0u;
            uu.y = ok ? uu.y : 0u;
            u1[k] = uu;
        }
        #pragma unroll
        for (int k = 0; k < 8; ++k) {
            a0 += __builtin_amdgcn_cvt_pk_f32_fp8(u0[k].x, false);
            a1 += __builtin_amdgcn_cvt_pk_f32_fp8(u0[k].x, true);
            a2 += __builtin_amdgcn_cvt_pk_f32_fp8(u0[k].y, false);
            a3 += __builtin_amdgcn_cvt_pk_f32_fp8(u0[k].y, true);
            b0 += __builtin_amdgcn_cvt_pk_f32_fp8(u1[k].x, false);
            b1 += __builtin_amdgcn_cvt_pk_f32_fp8(u1[k].x, true);
            b2 += __builtin_amdgcn_cvt_pk_f32_fp8(u1[k].y, false);
            b3 += __builtin_amdgcn_cvt_pk_f32_fp8(u1[k].y, true);
        }
    }
    float af[8] = {a0.x, a0.y, a1.x, a1.y, a2.x, a2.y, a3.x, a3.y};
    float bf[8] = {b0.x, b0.y, b1.x, b1.y, b2.x, b2.y, b3.x, b3.y};
    #pragma unroll
    for (int k = 0; k < 8; ++k) {
        af[k] += __shfl_xor(af[k], 16);
        af[k] += __shfl_xor(af[k], 32);
        bf[k] += __shfl_xor(bf[k], 16);
        bf[k] += __shfl_xor(bf[k], 32);
    }
    if (eg == 0) {
        float id0 = inv_deg[n0];
        float id1 = inv_deg[n1];
        #pragma unroll
        for (int nt = 0; nt < 8; ++nt) {
            aggb[(size_t)n0 * 128 + nt * 16 + j] = f2b(af[nt] * id0);
            aggb[(size_t)n1 * 128 + nt * 16 + j] = f2b(bf[nt] * id1);
        }
    }
}

// ---------------- mean pool per graph from bf16 (4 waves + LDS reduce) ------
__global__ __launch_bounds__(256)
void pool_mean_b(const unsigned short* __restrict__ src, const int* __restrict__ g_off,
                 const float* __restrict__ inv_cnt, float* __restrict__ out) {
    __shared__ float red[3][128];
    const int g = blockIdx.x;
    const int t = threadIdx.x;
    const int lane = t & 63, wid = t >> 6;
    const int j = lane & 15, rs = lane >> 4;
    const int beg = g_off[g], end = g_off[g + 1];
    float s[8] = {0.f, 0.f, 0.f, 0.f, 0.f, 0.f, 0.f, 0.f};
    for (int n = beg + rs + wid * 4; n < end; n += 16) {
        short8 v = *(const short8*)&src[(size_t)n * FF + j * 8];
        #pragma unroll
        for (int i = 0; i < 8; ++i) s[i] += us2f((unsigned short)v[i]);
    }
    #pragma unroll
    for (int i = 0; i < 8; ++i) {
        s[i] += __shfl_xor(s[i], 16);
        s[i] += __shfl_xor(s[i], 32);
    }
    if (wid > 0 && rs == 0) {
        #pragma unroll
        for (int i = 0; i < 8; ++i) red[wid - 1][j * 8 + i] = s[i];
    }
    __syncthreads();
    if (wid == 0 && rs == 0) {
        float ic = inv_cnt[g];
        #pragma unroll
        for (int i = 0; i < 8; ++i) {
            float v = s[i] + red[0][j * 8 + i] + red[1][j * 8 + i] + red[2][j * 8 + i];
            out[(size_t)g * FF + j * 8 + i] = v * ic;
        }
    }
}

// ---------------- MFMA bf16 GEMM: BARRIER-FREE (wave-private band stage) ----
template<bool AB16, bool R1, int RESM, int ACT, bool LN, bool OF32, bool OB16, bool OB8>
__global__ __launch_bounds__(256)
void gemm_mfma(const void* __restrict__ A_,
               const unsigned short* __restrict__ Wf,
               const float* __restrict__ bias,
               const float* __restrict__ rvec, const float* __restrict__ rrow,
               const float* __restrict__ res,
               const float* __restrict__ lng, const float* __restrict__ lnb,
               float* __restrict__ outf, unsigned short* __restrict__ outb,
               unsigned char* __restrict__ outb8, int M) {
    __shared__ short Al[64 * 136];

    const int t = threadIdx.x;
    const int lane = t & 63, wid = t >> 6;
    const int m0 = blockIdx.x * 64;
    const int cb = lane & 15, rq = lane >> 4;
    const int band = wid * 16;

    if (AB16) {
        const unsigned short* Ab = (const unsigned short*)A_;
        #pragma unroll
        for (int i2 = 0; i2 < 4; ++i2) {
            int i = lane + i2 * 64;
            int row = band + (i >> 4), seg = i & 15;
            int gr = m0 + row; if (gr >= M) gr = M - 1;
            *(uint4*)&Al[row * 136 + seg * 8] = *(const uint4*)&Ab[(size_t)gr * 128 + seg * 8];
        }
    } else {
        const float* Af = (const float*)A_;
        #pragma unroll
        for (int i2 = 0; i2 < 8; ++i2) {
            int i = lane + i2 * 64;
            int row = band + (i >> 5), seg = i & 31;
            int gr = m0 + row; if (gr >= M) gr = M - 1;
            float4 v = *(const float4*)&Af[(size_t)gr * 128 + seg * 4];
            ushort4 o = {f2b(v.x), f2b(v.y), f2b(v.z), f2b(v.w)};
            *(ushort4*)&Al[row * 136 + seg * 4] = o;
        }
    }
    // no barrier: all LDS traffic is band-local (same wave wrote it)

    f32x4 acc[8];
    #pragma unroll
    for (int nt = 0; nt < 8; ++nt) acc[nt] = (f32x4){0.f, 0.f, 0.f, 0.f};

    const int aoff_base = (band + cb) * 136 + rq * 8;
    for (int kc = 0; kc < 4; ++kc) {
        short8 a0 = *(const short8*)&Al[aoff_base + kc * 32];
        #pragma unroll
        for (int nt = 0; nt < 8; ++nt) {
            short8 b0 = *(const short8*)&Wf[(size_t)(kc * 8 + nt) * 512 + lane * 8];
            acc[nt] = MFMA(a0, b0, acc[nt]);
        }
    }

    float bs[8], rr[8], lg[8], lb[8];
    #pragma unroll
    for (int nt = 0; nt < 8; ++nt) {
        int col = nt * 16 + cb;
        bs[nt] = bias[col];
        if (R1) rr[nt] = rrow[col];
        if (LN) { lg[nt] = lng[col]; lb[nt] = lnb[col]; }
    }
    #pragma unroll
    for (int reg = 0; reg < 4; ++reg) {
        int m = m0 + band + rq * 4 + reg;
        int mc = m < M ? m : M - 1;
        float v[8];
        #pragma unroll
        for (int nt = 0; nt < 8; ++nt) v[nt] = acc[nt][reg] + bs[nt];
        if (R1) {
            float rv = rvec[mc];
            #pragma unroll
            for (int nt = 0; nt < 8; ++nt) v[nt] += rv * rr[nt];
        }
        if (RESM == 1) {
            #pragma unroll
            for (int nt = 0; nt < 8; ++nt) v[nt] += res[(size_t)mc * 128 + nt * 16 + cb];
        }
        if (ACT == 1) {
            #pragma unroll
            for (int nt = 0; nt < 8; ++nt) v[nt] = fast_elu(v[nt]);
        }
        if (LN) {
            float s1 = 0.f, s2 = 0.f;
            #pragma unroll
            for (int nt = 0; nt < 8; ++nt) { s1 += v[nt]; s2 += v[nt] * v[nt]; }
            #pragma unroll
            for (int o = 8; o >= 1; o >>= 1) { s1 += __shfl_xor(s1, o); s2 += __shfl_xor(s2, o); }
            float mu = s1 * (1.f / 128.f);
            float rs = rsqrtf(s2 * (1.f / 128.f) - mu * mu + 1e-5f);
            #pragma unroll
            for (int nt = 0; nt < 8; ++nt) v[nt] = (v[nt] - mu) * rs * lg[nt] + lb[nt];
        }
        if (m < M) {
            #pragma unroll
            for (int nt = 0; nt < 8; ++nt) {
                size_t o = (size_t)m * 128 + nt * 16 + cb;
                if (OF32) outf[o] = v[nt];
                if (OB16) outb[o] = f2b(v[nt]);
            }
            if (OB8) *(uint2*)&outb8[(size_t)m * 128 + cb * 8] = pk8(v);
        }
    }
}

// ---------------- fused GEMM chain: BARRIER-FREE (wave-private bands) -------
__global__ __launch_bounds__(256)
void gc_chain(const unsigned short* __restrict__ hin, const unsigned short* __restrict__ aggb,
              unsigned short* __restrict__ hout, unsigned char* __restrict__ h8out,
              const unsigned short* __restrict__ Wl_f, const unsigned short* __restrict__ Wr_f,
              const unsigned short* __restrict__ W1_f, const unsigned short* __restrict__ W2_f,
              const float* __restrict__ bl,
              const float* __restrict__ g1, const float* __restrict__ b1,
              const float* __restrict__ bb1, const float* __restrict__ bb2,
              const float* __restrict__ g2, const float* __restrict__ b2, int M) {
    __shared__ short Hl[64 * 136];     // h tile -> y1 tile
    __shared__ short Gl[64 * 136];     // agg tile -> elu(t) tile

    const int t = threadIdx.x;
    const int lane = t & 63, wid = t >> 6;
    const int m0 = blockIdx.x * 64;
    const int cb = lane & 15, rq = lane >> 4;
    const int band = wid * 16;
    const int aoff_base = (band + cb) * 136 + rq * 8;
    const int boff = lane * 8;

    #pragma unroll
    for (int i2 = 0; i2 < 4; ++i2) {
        int i = lane + i2 * 64;
        int row = band + (i >> 4), seg = i & 15;
        int gr = m0 + row; if (gr >= M) gr = M - 1;
        *(uint4*)&Hl[row * 136 + seg * 8] = *(const uint4*)&hin[(size_t)gr * 128 + seg * 8];
        *(uint4*)&Gl[row * 136 + seg * 8] = *(const uint4*)&aggb[(size_t)gr * 128 + seg * 8];
    }
    // no barrier: band-local LDS only

    f32x4 acc[8];
    #pragma unroll
    for (int nt = 0; nt < 8; ++nt) acc[nt] = (f32x4){0.f, 0.f, 0.f, 0.f};

    // ---- dual GEMM: acc = agg@Wl + h@Wr ----
    for (int kc = 0; kc < 4; ++kc) {
        short8 a0 = *(const short8*)&Gl[aoff_base + kc * 32];
        short8 a1 = *(const short8*)&Hl[aoff_base + kc * 32];
        #pragma unroll
        for (int nt = 0; nt < 8; ++nt) {
            const size_t wo = (size_t)(kc * 8 + nt) * 512 + boff;
            acc[nt] = MFMA(a0, *(const short8*)&Wl_f[wo], acc[nt]);
            acc[nt] = MFMA(a1, *(const short8*)&Wr_f[wo], acc[nt]);
        }
    }

    // ---- epilogue 1 (band-local): y1 = LN1(acc + bl + h) -> Hl + regs ----
    float y1r[4][8];
    {
        float bs[8], lg[8], lb[8];
        #pragma unroll
        for (int nt = 0; nt < 8; ++nt) {
            int col = nt * 16 + cb;
            bs[nt] = bl[col]; lg[nt] = g1[col]; lb[nt] = b1[col];
        }
        #pragma unroll
        for (int reg = 0; reg < 4; ++reg) {
            int r = band + rq * 4 + reg;
            float v[8];
            float s1 = 0.f, s2 = 0.f;
            #pragma unroll
            for (int nt = 0; nt < 8; ++nt) {
                v[nt] = acc[nt][reg] + bs[nt] + us2f((unsigned short)Hl[r * 136 + nt * 16 + cb]);
                s1 += v[nt]; s2 += v[nt] * v[nt];
            }
            #pragma unroll
            for (int o = 8; o >= 1; o >>= 1) { s1 += __shfl_xor(s1, o); s2 += __shfl_xor(s2, o); }
            float mu = s1 * (1.f / 128.f);
            float rs = rsqrtf(s2 * (1.f / 128.f) - mu * mu + 1e-5f);
            #pragma unroll
            for (int nt = 0; nt < 8; ++nt) {
                float y = (v[nt] - mu) * rs * lg[nt] + lb[nt];
                y1r[reg][nt] = y;
                Hl[r * 136 + nt * 16 + cb] = (short)f2b(y);
            }
        }
    }

    // ---- FF1 (band-local): t = elu(y1@W1 + bb1) -> Gl ----
    #pragma unroll
    for (int nt = 0; nt < 8; ++nt) acc[nt] = (f32x4){0.f, 0.f, 0.f, 0.f};
    for (int kc = 0; kc < 4; ++kc) {
        short8 a0 = *(const short8*)&Hl[aoff_base + kc * 32];
        #pragma unroll
        for (int nt = 0; nt < 8; ++nt)
            acc[nt] = MFMA(a0, *(const short8*)&W1_f[(size_t)(kc * 8 + nt) * 512 + boff], acc[nt]);
    }
    {
        float bs[8];
        #pragma unroll
        for (int nt = 0; nt < 8; ++nt) bs[nt] = bb1[nt * 16 + cb];
        #pragma unroll
        for (int reg = 0; reg < 4; ++reg) {
            int r = band + rq * 4 + reg;
            #pragma unroll
            for (int nt = 0; nt < 8; ++nt) {
                float v = fast_elu(acc[nt][reg] + bs[nt]);
                Gl[r * 136 + nt * 16 + cb] = (short)f2b(v);
            }
        }
    }

    // ---- FF2 (band-local): h' = LN2(t@W2 + bb2 + y1) -> global bf16 + fp8 --
    #pragma unroll
    for (int nt = 0; nt < 8; ++nt) acc[nt] = (f32x4){0.f, 0.f, 0.f, 0.f};
    for (int kc = 0; kc < 4; ++kc) {
        short8 a0 = *(const short8*)&Gl[aoff_base + kc * 32];
        #pragma unroll
        for (int nt = 0; nt < 8; ++nt)
            acc[nt] = MFMA(a0, *(const short8*)&W2_f[(size_t)(kc * 8 + nt) * 512 + boff], acc[nt]);
    }
    {
        float bs[8], lg[8], lb[8];
        #pragma unroll
        for (int nt = 0; nt < 8; ++nt) {
            int col = nt * 16 + cb;
            bs[nt] = bb2[col]; lg[nt] = g2[col]; lb[nt] = b2[col];
        }
        #pragma unroll
        for (int reg = 0; reg < 4; ++reg) {
            int r = band + rq * 4 + reg;
            int m = m0 + r;
            float v[8];
            float s1 = 0.f, s2 = 0.f;
            #pragma unroll
            for (int nt = 0; nt < 8; ++nt) {
                v[nt] = acc[nt][reg] + bs[nt] + y1r[reg][nt];
                s1 += v[nt]; s2 += v[nt] * v[nt];
            }
            #pragma unroll
            for (int o = 8; o >= 1; o >>= 1) { s1 += __shfl_xor(s1, o); s2 += __shfl_xor(s2, o); }
            float mu = s1 * (1.f / 128.f);
            float rs = rsqrtf(s2 * (1.f / 128.f) - mu * mu + 1e-5f);
            if (m < M) {
                float fv[8];
                #pragma unroll
                for (int nt = 0; nt < 8; ++nt) {
                    fv[nt] = (v[nt] - mu) * rs * lg[nt] + lb[nt];
                    hout[(size_t)m * 128 + nt * 16 + cb] = f2b(fv[nt]);
                }
                *(uint2*)&h8out[(size_t)m * 128 + cb * 8] = pk8(fv);
            }
        }
    }
}

// ---------------- fused head: BARRIER-FREE band-local chain -----------------
__global__ __launch_bounds__(256)
void head_chain(const float* __restrict__ gm,
                const unsigned short* __restrict__ Wa_f,
                const unsigned short* __restrict__ P1_f,
                const unsigned short* __restrict__ P2_f,
                const float* __restrict__ mdfb,
                const float* __restrict__ g1, const float* __restrict__ b1,
                const float* __restrict__ p1b, const float* __restrict__ p2b,
                const float* __restrict__ g2, const float* __restrict__ b2,
                float* __restrict__ outp) {
    __shared__ short Al[64 * 136];

    const int t = threadIdx.x;
    const int lane = t & 63, wid = t >> 6;
    const int m0 = blockIdx.x * 64;
    const int cb = lane & 15, rq = lane >> 4;
    const int band = wid * 16;
    const int aoff_base = (band + cb) * 136 + rq * 8;
    const int boff = lane * 8;

    #pragma unroll
    for (int i2 = 0; i2 < 8; ++i2) {
        int i = lane + i2 * 64;
        int row = band + (i >> 5), seg = i & 31;
        float4 v = *(const float4*)&gm[(size_t)(m0 + row) * 128 + seg * 4];
        ushort4 o = {f2b(v.x), f2b(v.y), f2b(v.z), f2b(v.w)};
        *(ushort4*)&Al[row * 136 + seg * 4] = o;
    }
    // no barrier: band-local LDS only

    f32x4 acc[8];
    // ---- GEMM1: gm@Wa + mdfb, LN1 -> y1r + Al ----
    #pragma unroll
    for (int nt = 0; nt < 8; ++nt) acc[nt] = (f32x4){0.f, 0.f, 0.f, 0.f};
    for (int kc = 0; kc < 4; ++kc) {
        short8 a0 = *(const short8*)&Al[aoff_base + kc * 32];
        #pragma unroll
        for (int nt = 0; nt < 8; ++nt)
            acc[nt] = MFMA(a0, *(const short8*)&Wa_f[(size_t)(kc * 8 + nt) * 512 + boff], acc[nt]);
    }
    float y1r[4][8];
    {
        float bs[8], lg[8], lb[8];
        #pragma unroll
        for (int nt = 0; nt < 8; ++nt) {
            int col = nt * 16 + cb;
            bs[nt] = mdfb[col]; lg[nt] = g1[col]; lb[nt] = b1[col];
        }
        #pragma unroll
        for (int reg = 0; reg < 4; ++reg) {
            int r = band + rq * 4 + reg;
            float v[8];
            float s1 = 0.f, s2 = 0.f;
            #pragma unroll
            for (int nt = 0; nt < 8; ++nt) {
                v[nt] = acc[nt][reg] + bs[nt];
                s1 += v[nt]; s2 += v[nt] * v[nt];
            }
            #pragma unroll
            for (int o = 8; o >= 1; o >>= 1) { s1 += __shfl_xor(s1, o); s2 += __shfl_xor(s2, o); }
            float mu = s1 * (1.f / 128.f);
            float rs = rsqrtf(s2 * (1.f / 128.f) - mu * mu + 1e-5f);
            #pragma unroll
            for (int nt = 0; nt < 8; ++nt) {
                float y = (v[nt] - mu) * rs * lg[nt] + lb[nt];
                y1r[reg][nt] = y;
                Al[r * 136 + nt * 16 + cb] = (short)f2b(y);
            }
        }
    }

    // ---- GEMM2: elu(y1@P1 + p1b) -> Al ----
    #pragma unroll
    for (int nt = 0; nt < 8; ++nt) acc[nt] = (f32x4){0.f, 0.f, 0.f, 0.f};
    for (int kc = 0; kc < 4; ++kc) {
        short8 a0 = *(const short8*)&Al[aoff_base + kc * 32];
        #pragma unroll
        for (int nt = 0; nt < 8; ++nt)
            acc[nt] = MFMA(a0, *(const short8*)&P1_f[(size_t)(kc * 8 + nt) * 512 + boff], acc[nt]);
    }
    {
        float bs[8];
        #pragma unroll
        for (int nt = 0; nt < 8; ++nt) bs[nt] = p1b[nt * 16 + cb];
        #pragma unroll
        for (int reg = 0; reg < 4; ++reg) {
            int r = band + rq * 4 + reg;
            #pragma unroll
            for (int nt = 0; nt < 8; ++nt) {
                float v = fast_elu(acc[nt][reg] + bs[nt]);
                Al[r * 136 + nt * 16 + cb] = (short)f2b(v);
            }
        }
    }

    // ---- GEMM3: LN2(t@P2 + p2b + y1r) -> out fp32 ----
    #pragma unroll
    for (int nt = 0; nt < 8; ++nt) acc[nt] = (f32x4){0.f, 0.f, 0.f, 0.f};
    for (int kc = 0; kc < 4; ++kc) {
        short8 a0 = *(const short8*)&Al[aoff_base + kc * 32];
        #pragma unroll
        for (int nt = 0; nt < 8; ++nt)
            acc[nt] = MFMA(a0, *(const short8*)&P2_f[(size_t)(kc * 8 + nt) * 512 + boff], acc[nt]);
    }
    {
        float bs[8], lg[8], lb[8];
        #pragma unroll
        for (int nt = 0; nt < 8; ++nt) {
            int col = nt * 16 + cb;
            bs[nt] = p2b[col]; lg[nt] = g2[col]; lb[nt] = b2[col];
        }
        #pragma unroll
        for (int reg = 0; reg < 4; ++reg) {
            int r = band + rq * 4 + reg;
            int m = m0 + r;
            float v[8];
            float s1 = 0.f, s2 = 0.f;
            #pragma unroll
            for (int nt = 0; nt < 8; ++nt) {
                v[nt] = acc[nt][reg] + bs[nt] + y1r[reg][nt];
                s1 += v[nt]; s2 += v[nt] * v[nt];
            }
            #pragma unroll
            for (int o = 8; o >= 1; o >>= 1) { s1 += __shfl_xor(s1, o); s2 += __shfl_xor(s2, o); }
            float mu = s1 * (1.f / 128.f);
            float rs = rsqrtf(s2 * (1.f / 128.f) - mu * mu + 1e-5f);
            #pragma unroll
            for (int nt = 0; nt < 8; ++nt)
                outp[(size_t)m * 128 + nt * 16 + cb] = (v[nt] - mu) * rs * lg[nt] + lb[nt];
        }
    }
}

extern "C" void kernel_launch(void* const* d_in, const int* in_sizes, int n_in,
                              void* d_out, int out_size, void* d_ws, size_t ws_size,
                              hipStream_t stream) {
    const float* x      = (const float*)d_in[0];
    const float* w      = (const float*)d_in[1];
    const int*   ei     = (const int*)d_in[2];
    const int*   batch  = (const int*)d_in[3];
    const float* W_in   = (const float*)d_in[4];
    const float* b_in   = (const float*)d_in[5];
    const float* sage_Wl = (const float*)d_in[6];
    const float* sage_bl = (const float*)d_in[7];
    const float* sage_Wr = (const float*)d_in[8];
    const float* ln1_g  = (const float*)d_in[9];
    const float* ln1_b  = (const float*)d_in[10];
    const float* lin1_W = (const float*)d_in[11];
    const float* lin1_b = (const float*)d_in[12];
    const float* lin2_W = (const float*)d_in[13];
    const float* lin2_b = (const float*)d_in[14];
    const float* ln2_g  = (const float*)d_in[15];
    const float* ln2_b  = (const float*)d_in[16];
    const float* mdf_W  = (const float*)d_in[17];
    const float* mdf_b  = (const float*)d_in[18];
    const float* pln1_g = (const float*)d_in[19];
    const float* pln1_b = (const float*)d_in[20];
    const float* plin1_W = (const float*)d_in[21];
    const float* plin1_b = (const float*)d_in[22];
    const float* plin2_W = (const float*)d_in[23];
    const float* plin2_b = (const float*)d_in[24];
    const float* pln2_g = (const float*)d_in[25];
    const float* pln2_b = (const float*)d_in[26];
    float* out = (float*)d_out;

    const int* e_src = ei;
    const int* e_dst = ei + NE;

    // ---- workspace layout ----
    float* ws = (float*)d_ws;
    size_t off = 0;
    float* gm    = ws + off; off += (size_t)NG * FF;
    float* inv_deg = ws + off; off += NN;
    float* inv_cnt = ws + off; off += NG;
    unsigned short* us = (unsigned short*)(ws + off);
    size_t uoff = 0;
    unsigned short* hb0  = us + uoff; uoff += (size_t)NN * FF;
    unsigned short* hb1  = us + uoff; uoff += (size_t)NN * FF;
    unsigned short* aggb = us + uoff; uoff += (size_t)NN * FF;
    unsigned short* wt   = us + uoff; uoff += (size_t)16 * 16384;
    int* iw = (int*)(us + uoff);
    size_t ioff = 0;
    unsigned* pairs = (unsigned*)iw; ioff += (size_t)NBK * BCAP;
    int* ssrc    = iw + ioff; ioff += (size_t)NBK * BCAP;
    int* row_beg = iw + ioff; ioff += NN;
    int* row_end = iw + ioff; ioff += NN;
    int* g_off   = iw + ioff; ioff += NG + 1;
    int* bcur    = iw + ioff; ioff += NBK;
    // h8 (12.8 MB) aliases pairs (12.85 MB): pairs is dead after bucket_build,
    // h8 is first written by the input GEMM which runs after.
    unsigned char* h8 = (unsigned char*)pairs;

    // ---- weight prep (16 matrices, coalesced via LDS) + bcur/sentinel ----
    WTab tab;
    tab.a[0] = W_in;
    for (int l = 0; l < 3; ++l) {
        tab.a[1 + l]  = sage_Wl + (size_t)l * 16384;
        tab.a[4 + l]  = sage_Wr + (size_t)l * 16384;
        tab.a[7 + l]  = lin1_W + (size_t)l * 16384;
        tab.a[10 + l] = lin2_W + (size_t)l * 16384;
    }
    tab.a[13] = mdf_W;      // first 128 rows only (Wa)
    tab.a[14] = plin1_W;
    tab.a[15] = plin2_W;
    prep_weights<<<16, 256, 0, stream>>>(tab, wt, bcur, ssrc);
    const unsigned short* win_t = wt + 0 * 16384;
    const unsigned short* wa_t  = wt + 13 * 16384;
    const unsigned short* p1_t  = wt + 14 * 16384;
    const unsigned short* p2_t  = wt + 15 * 16384;

    // ---- build padded CSR (graph offsets folded into bucket_build) ----
    radix_scatter<<<RB, 256, 0, stream>>>(e_src, e_dst, bcur, pairs, NE);
    bucket_build<<<NBK, 512, 0, stream>>>(pairs, bcur, row_beg, row_end,
                                          inv_deg, ssrc, batch, g_off, inv_cnt);

    const int GN = (NN + 63) / 64;     // 1563
    const int GB = NG / 64;            // 16

    // ---- input linear: hb0 (bf16) + h8 (fp8, permuted) ----
    gemm_mfma<false, true, 0, 0, false, false, true, true><<<GN, 256, 0, stream>>>(
        x, win_t, b_in, w, W_in + 128 * 128,
        nullptr, nullptr, nullptr, nullptr, hb0, h8, NN);

    // ---- 3 GC blocks: fp8 gather + fused GEMM chain ----
    unsigned short* hcur = hb0;
    unsigned short* hnxt = hb1;
    for (int l = 0; l < 3; ++l) {
        sage_agg<<<NN / 8, 256, 0, stream>>>(h8, row_beg, row_end, inv_deg, ssrc, aggb);
        gc_chain<<<GN, 256, 0, stream>>>(
            hcur, aggb, hnxt, h8,
            wt + (size_t)(1 + l) * 16384, wt + (size_t)(4 + l) * 16384,
            wt + (size_t)(7 + l) * 16384, wt + (size_t)(10 + l) * 16384,
            sage_bl + (size_t)l * FF,
            ln1_g + (size_t)l * FF, ln1_b + (size_t)l * FF,
            lin1_b + (size_t)l * FF, lin2_b + (size_t)l * FF,
            ln2_g + (size_t)l * FF, ln2_b + (size_t)l * FF, NN);
        unsigned short* tmp = hcur; hcur = hnxt; hnxt = tmp;
    }

    // ---- head: pool(h2) -> fused LN1/FF/LN2 chain (one launch) ----
    pool_mean_b<<<NG, 256, 0, stream>>>(hcur, g_off, inv_cnt, gm);
    head_chain<<<GB, 256, 0, stream>>>(
        gm, wa_t, p1_t, p2_t, mdf_b,
        pln1_g, pln1_b, plin1_b, plin2_b, pln2_g, pln2_b, out);
}